// Round 10
// baseline (181.110 us; speedup 1.0000x reference)
//
#include <hip/hip_runtime.h>
#include <stdint.h>
#include <stddef.h>

// RadialCTC: cosine logits (norm_scale=32) -> log_softmax -> CTC(sum).
// Strategy: never materialize the (16384 x 1296) logits. GEMM (f16 MFMA)
// computes per-row sum(exp(logit)) fused in the epilogue; label log-probs via
// small f16 MFMA gather-GEMM; CTC alpha recursion one wave per sample.
// R4: gather on MFMA. R5: shfl=ds_bpermute ~120cyc; fp8 non-scaled = f16 rate.
// R6: DPP wave_shr neighbor access. R7: log-domain pair-fusion regressed
//     (lse3 = 2 transcendental layers itself); gather single-barrier kept.
// R8: linear f32 FAILED (cross-lane spread > f32 window).
// R9: linear f64 + exact pow2 renorm: works, ~30us = 144 cyc/step (f64 dep
//     latency + DPP old-operand movs heavier than modeled).
// R10: (a) ctc 2-step fusion IN LINEAR DOMAIN: beta' = sum c_k * (beta>>k),
//      c_k built off-chain in f32 from P=2^lp and constant skip flags; only
//      ONE lp stream; renorm every 8 steps. (b) gemm epilogue column-sums on
//      VALU DPP ROW_ROR cascade instead of shfl_xor (LDS pipe); sumexp
//      relaid out to [n][t] so gather's lse load coalesces.

typedef _Float16 f16;
typedef _Float16 f16x8 __attribute__((ext_vector_type(8)));
typedef float f32x4 __attribute__((ext_vector_type(4)));
typedef __attribute__((address_space(1))) void* as1_void_ptr;
typedef __attribute__((address_space(3))) void* as3_void_ptr;

#define TT 512
#define NN 32
#define CC 1296
#define DD 512
#define SS 30
#define CP 1408   // C padded to 11*128 for GEMM tiling (pad rows are zero)
#define LL 61     // 2*S+1 CTC states
#define NEGINF (-1e9f)
#define NORM_SCALE 32.0f
#define LOG2E 1.4426950408889634f
#define LN2   0.6931471805599453f

__device__ __forceinline__ float fexp2(float x) { return __builtin_amdgcn_exp2f(x); }
__device__ __forceinline__ float flog2(float x) { return __builtin_amdgcn_logf(x); }

// whole-wave shift-right-by-1 (DPP ctrl 0x138 = WAVE_SHR1); lane0 <- 0
__device__ __forceinline__ float dpp_sr1_zero_f32(float x) {
    return __int_as_float(__builtin_amdgcn_update_dpp(
        0, __float_as_int(x), 0x138, 0xF, 0xF, false));
}
__device__ __forceinline__ double dpp_sr1_zero64(double x) {
    long long b = __double_as_longlong(x);
    int lo = (int)(b & 0xFFFFFFFFLL);
    int hi = (int)(b >> 32);
    int lo2 = __builtin_amdgcn_update_dpp(0, lo, 0x138, 0xF, 0xF, false);
    int hi2 = __builtin_amdgcn_update_dpp(0, hi, 0x138, 0xF, 0xF, false);
    return __longlong_as_double(((long long)hi2 << 32) |
                                (unsigned long long)(unsigned int)lo2);
}
// one level of DPP row-shr int max (identity 0; operands >=0)
template <int CTRL>
__device__ __forceinline__ int dpp_imax_level(int m) {
    int t = __builtin_amdgcn_update_dpp(0, m, CTRL, 0xF, 0xF, false);
    return m > t ? m : t;
}
// one level of DPP row-rotate f32 add (sum over 16-lane row via 8,4,2,1)
template <int CTRL>
__device__ __forceinline__ float dpp_add_level(float m) {
    float t = __int_as_float(__builtin_amdgcn_update_dpp(
        0, __float_as_int(m), CTRL, 0xF, 0xF, false));
    return m + t;
}

// ---- col sum-of-squares of W (D x C), partial over d-chunks, atomic ----
__global__ void colnorm_kernel(const float* __restrict__ W, float* __restrict__ ssq) {
    int c = blockIdx.x * 64 + threadIdx.x;
    if (c >= CC) return;
    int d0 = blockIdx.y * 64;
    float ss = 0.f;
    #pragma unroll 8
    for (int d = d0; d < d0 + 64; ++d) {
        float v = W[(size_t)d * CC + c];
        ss += v * v;
    }
    atomicAdd(&ssq[c], ss);
}

// ---- build padded transposed normalized weight w_t (CP x DD), f16 ----
__global__ void wt_kernel(const float* __restrict__ W, const float* __restrict__ ssq,
                          f16* __restrict__ wt) {
    int idx = blockIdx.x * 256 + threadIdx.x;   // idx < CP*DD
    int c = idx >> 9, d = idx & 511;
    float v = 0.f;
    if (c < CC) v = W[(size_t)d * CC + c] * rsqrtf(ssq[c]);
    wt[idx] = (f16)v;
}

// ---- feats row-normalize -> f16 (one wave per row) ----
__global__ __launch_bounds__(256) void fnorm_kernel(const float* __restrict__ feats,
                                                    f16* __restrict__ fn) {
    int wv = (blockIdx.x * 256 + threadIdx.x) >> 6;  // row id, 0..16383
    int lane = threadIdx.x & 63;
    const float4* src = (const float4*)(feats + (size_t)wv * DD) + lane * 2;
    float4 a = src[0], b = src[1];
    float ss = a.x*a.x + a.y*a.y + a.z*a.z + a.w*a.w
             + b.x*b.x + b.y*b.y + b.z*b.z + b.w*b.w;
    #pragma unroll
    for (int off = 32; off; off >>= 1) ss += __shfl_xor(ss, off);
    float r = rsqrtf(ss);
    f16x8 o;
    o[0]=(f16)(a.x*r); o[1]=(f16)(a.y*r); o[2]=(f16)(a.z*r); o[3]=(f16)(a.w*r);
    o[4]=(f16)(b.x*r); o[5]=(f16)(b.y*r); o[6]=(f16)(b.z*r); o[7]=(f16)(b.w*r);
    *(f16x8*)(fn + (size_t)wv * DD + lane * 8) = o;
}

// ---- MFMA GEMM (A: 16384x512 f16, B^T: 1408x512 f16) with fused
//      row-wise sum(exp(32*dot)) epilogue -> atomicAdd into sumexp[n][t] ----
__global__ __launch_bounds__(256) void gemm_sumexp_kernel(const f16* __restrict__ A,
                                                          const f16* __restrict__ B,
                                                          float* __restrict__ sumexp) {
    __shared__ __align__(16) f16 As[128 * 32];
    __shared__ __align__(16) f16 Bs[128 * 32];
    int bm = blockIdx.x, bn = blockIdx.y;
    int tid = threadIdx.x;
    int w = tid >> 6, lane = tid & 63;
    int wm = w >> 1, wn = w & 1;           // 2x2 wave grid -> 64x64 per wave
    int lm = lane & 15, hi = lane >> 4;
    f32x4 acc[4][4];
    f32x4 zero = {0.f, 0.f, 0.f, 0.f};
    #pragma unroll
    for (int i = 0; i < 4; ++i)
        #pragma unroll
        for (int j = 0; j < 4; ++j) acc[i][j] = zero;

    for (int kb = 0; kb < 16; ++kb) {      // K=512, BK=32 (one MFMA K-step)
        #pragma unroll
        for (int p = 0; p < 2; ++p) {
            int s = p * 256 + tid;         // segment id, 16B each; 512 segs/tile
            int row = s >> 2, ch = s & 3;
            const f16* ga = A + (size_t)(bm * 128 + row) * DD + kb * 32 + ch * 8;
            const f16* gb = B + (size_t)(bn * 128 + row) * DD + kb * 32 + ch * 8;
            // LDS dest = wave-uniform base + lane*16
            __builtin_amdgcn_global_load_lds((as1_void_ptr)ga,
                (as3_void_ptr)&As[(p * 256 + w * 64) * 8], 16, 0, 0);
            __builtin_amdgcn_global_load_lds((as1_void_ptr)gb,
                (as3_void_ptr)&Bs[(p * 256 + w * 64) * 8], 16, 0, 0);
        }
        __syncthreads();
        f16x8 af[4], bf[4];
        #pragma unroll
        for (int i = 0; i < 4; ++i)
            af[i] = *(const f16x8*)&As[(wm * 64 + i * 16 + lm) * 32 + hi * 8];
        #pragma unroll
        for (int j = 0; j < 4; ++j)
            bf[j] = *(const f16x8*)&Bs[(wn * 64 + j * 16 + lm) * 32 + hi * 8];
        #pragma unroll
        for (int i = 0; i < 4; ++i)
            #pragma unroll
            for (int j = 0; j < 4; ++j)
                acc[i][j] = __builtin_amdgcn_mfma_f32_16x16x32_f16(af[i], bf[j], acc[i][j], 0, 0, 0);
        __syncthreads();
    }
    // epilogue: per-row sum of exp(32*logit) over this block's 128 columns.
    // 16-lane column sum on the VALU pipe (DPP ROW_ROR 8/4/2/1), not shfl_xor.
    #pragma unroll
    for (int i = 0; i < 4; ++i) {
        float rs[4] = {0.f, 0.f, 0.f, 0.f};
        #pragma unroll
        for (int j = 0; j < 4; ++j) {
            int c = bn * 128 + wn * 64 + j * 16 + lm;   // C/D: col = lane&15
            bool ok = (c < CC);
            #pragma unroll
            for (int r = 0; r < 4; ++r)
                rs[r] += ok ? fexp2(acc[i][j][r] * (NORM_SCALE * LOG2E)) : 0.f;
        }
        #pragma unroll
        for (int r = 0; r < 4; ++r) {
            float m = rs[r];
            m = dpp_add_level<0x128>(m);   // row_ror:8
            m = dpp_add_level<0x124>(m);   // row_ror:4
            m = dpp_add_level<0x122>(m);   // row_ror:2
            m = dpp_add_level<0x121>(m);   // row_ror:1
            rs[r] = m;
        }
        if (lm == 0) {
            int rowb = bm * 128 + wm * 64 + i * 16 + hi * 4;  // row = quad*4+reg
            #pragma unroll
            for (int r = 0; r < 4; ++r) {
                int row = rowb + r;        // row = t*32 + n
                atomicAdd(&sumexp[(row & 31) * TT + (row >> 5)], rs[r]);
            }
        }
    }
}

// ---- gather-GEMM (f16): per (n, 64-t chunk), P = Fn(64x512) x Wlab^T(32x512).
//      All 16 K-tiles staged up-front (A 64KB + B 32KB LDS), ONE barrier. ----
__global__ __launch_bounds__(256) void gather_kernel(const f16* __restrict__ fn,
                                                     const f16* __restrict__ wt,
                                                     const float* __restrict__ sumexp,
                                                     const int* __restrict__ labels,
                                                     float* __restrict__ lp_lab) {
    __shared__ __align__(16) f16 Bs[16 * 32 * 32];   // 32 KB: [kb][row][kk]
    __shared__ __align__(16) f16 As[16 * 64 * 32];   // 64 KB: [kb][row][kk]
    __shared__ float ls2[64];
    int n = blockIdx.x, t0 = blockIdx.y * 64;
    int tid = threadIdx.x;
    int w = tid >> 6, lane = tid & 63;
    int lm = lane & 15, hi = lane >> 4;

    #pragma unroll
    for (int it = 0; it < 8; ++it) {       // B: 2048 segs of 16B
        int s = it * 256 + tid;            // kb = s>>7, row = (s>>2)&31, ch = s&3
        int row = (s >> 2) & 31;
        int cls = (row == 0 || row > SS) ? 0 : labels[n * SS + row - 1];
        const f16* gb = wt + (size_t)cls * DD + (s >> 7) * 32 + (s & 3) * 8;
        __builtin_amdgcn_global_load_lds((as1_void_ptr)gb,
            (as3_void_ptr)&Bs[(it * 256 + w * 64) * 8], 16, 0, 0);
    }
    #pragma unroll
    for (int it = 0; it < 16; ++it) {      // A: 4096 segs of 16B
        int s = it * 256 + tid;            // kb = s>>8, row = (s>>2)&63, ch = s&3
        int kb = s >> 8, row = (s >> 2) & 63, ch = s & 3;
        const f16* ga = fn + (size_t)((t0 + row) * NN + n) * DD + kb * 32 + ch * 8;
        __builtin_amdgcn_global_load_lds((as1_void_ptr)ga,
            (as3_void_ptr)&As[(it * 256 + w * 64) * 8], 16, 0, 0);
    }
    if (tid < 64) ls2[tid] = flog2(sumexp[(size_t)n * TT + t0 + tid]);
    __syncthreads();

    f32x4 acc[2];
    acc[0] = (f32x4){0.f, 0.f, 0.f, 0.f};
    acc[1] = (f32x4){0.f, 0.f, 0.f, 0.f};
    #pragma unroll
    for (int kb = 0; kb < 16; ++kb) {
        f16x8 af  = *(const f16x8*)&As[kb * 2048 + (w * 16 + lm) * 32 + hi * 8];
        f16x8 bf0 = *(const f16x8*)&Bs[kb * 1024 + lm * 32 + hi * 8];
        f16x8 bf1 = *(const f16x8*)&Bs[kb * 1024 + (16 + lm) * 32 + hi * 8];
        acc[0] = __builtin_amdgcn_mfma_f32_16x16x32_f16(af, bf0, acc[0], 0, 0, 0);
        acc[1] = __builtin_amdgcn_mfma_f32_16x16x32_f16(af, bf1, acc[1], 0, 0, 0);
    }
    #pragma unroll
    for (int jn = 0; jn < 2; ++jn) {
        int j = jn * 16 + lm;
        if (j >= 31) continue;
        float* dst = lp_lab + ((size_t)n * 31 + j) * TT + t0;
        #pragma unroll
        for (int r = 0; r < 4; ++r) {
            int tl = w * 16 + hi * 4 + r;
            dst[tl] = acc[jn][r] * (NORM_SCALE * LOG2E) - ls2[tl];
        }
    }
}

// ---- CTC alpha recursion, LINEAR f64, 2-step fused: one wave/sample.
//      beta' = c0*b0 + c1*(b>>1) + c2*(b>>2) + c3*(b>>3) + c4*(b>>4), with
//      c_k built OFF-chain in f32 from P=2^lp and constant skip flags.
//      Wave-uniform exact pow2 renorm every 8 steps; loop bound = Tin. ----
__global__ void ctc_kernel(const float* __restrict__ lp_lab, const int* __restrict__ labels,
                           const int* __restrict__ in_lens, const int* __restrict__ lab_lens,
                           float* __restrict__ nll) {
    int n = blockIdx.x;
    int s = threadIdx.x;     // 64 lanes; states 0..60 valid
    bool valid = s < LL;
    int ext = (valid && (s & 1)) ? labels[n * SS + (s >> 1)] : 0;
    int jmap = (valid && (s & 1)) ? ((s >> 1) + 1) : 0;   // state -> class slot
    int ext2 = __shfl_up(ext, 2);
    bool skip0 = (s >= 2) && valid && (ext != ext2);
    float kf = skip0 ? 1.f : 0.f;           // skip flag of state s
    float k1 = (s >= 1) ? __shfl_up(kf, 1) : 0.f;   // of state s-1 (prologue only)
    float k2 = (s >= 2) ? __shfl_up(kf, 2) : 0.f;   // of state s-2
    float kk2 = kf * k2;
    double skipd = (double)kf;
    int Tin = in_lens[n];    // wave-uniform; freeze == stop at t = Tin-1
    const float4* g0 = (const float4*)(lp_lab + ((size_t)n * 31 + jmap) * TT);

    float4 cur = g0[0];
    float4 nxt = g0[1];
    float4 nx2 = g0[2];
    double beta = (s <= 1) ? (double)fexp2(cur.x) : 0.0;
    int Mi = 0;              // running log2 scale

    auto stepL = [&](float lp) {           // single unfused step (t=1, tail)
        double P = (double)fexp2(lp);
        double b1 = dpp_sr1_zero64(beta);
        double b2 = dpp_sr1_zero64(b1);
        beta = (beta + b1 + b2 * skipd) * P;
    };
    auto pair2 = [&](float lpA, float lpB) {   // 2 fused steps
        float P1 = fexp2(lpA), P2 = fexp2(lpB);
        float P1m1 = dpp_sr1_zero_f32(P1);     // P_t of state s-1
        float P1m2 = dpp_sr1_zero_f32(P1m1);   // P_t of state s-2
        float kP1m2 = kf * P1m2;
        float c0 = P2 * P1;
        float c1 = P2 * (P1 + P1m1);
        float c2 = P2 * (kf * P1 + P1m1 + kP1m2);
        float c3 = P2 * (k1 * P1m1 + kP1m2);
        float c4 = P2 * (kk2 * P1m2);
        double b1 = dpp_sr1_zero64(beta);
        double b2 = dpp_sr1_zero64(b1);
        double b3 = dpp_sr1_zero64(b2);
        double b4 = dpp_sr1_zero64(b3);
        double a01 = (double)c0 * beta + (double)c1 * b1;
        double a23 = (double)c2 * b2 + (double)c3 * b3;
        beta = a01 + a23 + (double)c4 * b4;
    };
    auto renorm = [&]() {
        int h = (int)(__double_as_longlong(beta) >> 32);  // beta>=0: monotone
        h = dpp_imax_level<0x111>(h);        // row_shr:1
        h = dpp_imax_level<0x112>(h);        // row_shr:2
        h = dpp_imax_level<0x114>(h);        // row_shr:4
        h = dpp_imax_level<0x118>(h);        // row_shr:8 -> row max in 15/31/47/63
        int r0 = __builtin_amdgcn_readlane(h, 15);
        int r1 = __builtin_amdgcn_readlane(h, 31);
        int r2 = __builtin_amdgcn_readlane(h, 47);
        int r3 = __builtin_amdgcn_readlane(h, 63);
        int mx = max(max(r0, r1), max(r2, r3));
        int e11 = mx >> 20;                  // biased 11-bit exponent
        double scale = __longlong_as_double((long long)(2046 - e11) << 52);
        beta *= scale;                       // exact power-of-2
        Mi += e11 - 1023;
    };

    // t=1 single (realign), fused pair (t=2,3), renorm (Tin >= 481)
    stepL(cur.y);
    pair2(cur.z, cur.w);
    renorm();
    int remaining = Tin - 4;   // steps left (total steps = Tin-1)
    int g = 1;
    while (remaining >= 4) {
        cur = nxt; nxt = nx2;
        int gi = g + 2; if (gi > 127) gi = 127;
        nx2 = g0[gi];
        pair2(cur.x, cur.y);
        pair2(cur.z, cur.w);
        if (g & 1) renorm();   // every 2 groups = 8 steps (f64 window ample)
        remaining -= 4; ++g;
    }
    cur = nxt;                 // tail 0..3 single steps (no renorm needed:
    if (remaining > 0) stepL(cur.x);   // <=11 steps decay stays normal f64)
    if (remaining > 1) stepL(cur.y);
    if (remaining > 2) stepL(cur.z);

    int Ln = 2 * lab_lens[n] + 1;
    double last  = __shfl(beta, Ln - 1);
    double last2 = __shfl(beta, Ln - 2);
    double sm = last + last2;
    // log2 from the double's own exponent+mantissa (no tiny-f64 -> f32 cast)
    long long bb = __double_as_longlong(sm);
    int e = (int)(bb >> 52) - 1023;
    double mant = __longlong_as_double((bb & 0xFFFFFFFFFFFFFLL) | (1023LL << 52));
    float v = -(flog2((float)mant) + (float)(e + Mi)) * LN2;
    if (s == 0) nll[n] = v;
}

__global__ void reduce_kernel(const float* __restrict__ nll, float* __restrict__ out) {
    int s = threadIdx.x;
    float v = (s < NN) ? nll[s] : 0.f;
    #pragma unroll
    for (int off = 32; off; off >>= 1) v += __shfl_xor(v, off);
    if (s == 0) out[0] = v;
}

extern "C" void kernel_launch(void* const* d_in, const int* in_sizes, int n_in,
                              void* d_out, int out_size, void* d_ws, size_t ws_size,
                              hipStream_t stream) {
    const float* feats        = (const float*)d_in[0];
    const float* W            = (const float*)d_in[1];
    const int*   labeling     = (const int*)d_in[2];
    const int*   logit_lgts   = (const int*)d_in[3];
    const int*   labeling_lgts= (const int*)d_in[4];
    float* out = (float*)d_out;
    char* ws = (char*)d_ws;

    size_t off = 0;
    f16*   wt     = (f16*)(ws + off);   off += (size_t)CP * DD * 2;        // 1.44 MB
    f16*   fn     = (f16*)(ws + off);   off += (size_t)TT * NN * DD * 2;   // 16.8 MB
    float* ssq    = (float*)(ws + off); off += 1312 * 4;
    float* sumexp = (float*)(ws + off); off += (size_t)TT * NN * 4;        // 64 KB, [n][t]
    float* lp_lab = (float*)(ws + off); off += (size_t)NN * 31 * TT * 4;   // 2.0 MB
    float* nllb   = (float*)(ws + off); off += 64 * 4;

    hipMemsetAsync(ssq, 0, 1312 * 4, stream);
    hipMemsetAsync(sumexp, 0, (size_t)TT * NN * 4, stream);

    colnorm_kernel<<<dim3((CC + 63) / 64, 8), 64, 0, stream>>>(W, ssq);
    wt_kernel<<<(CP * DD) / 256, 256, 0, stream>>>(W, ssq, wt);
    fnorm_kernel<<<(TT * NN) / 4, 256, 0, stream>>>(feats, fn);
    gemm_sumexp_kernel<<<dim3(TT * NN / 128, CP / 128), 256, 0, stream>>>(fn, wt, sumexp);
    gather_kernel<<<dim3(NN, TT / 64), 256, 0, stream>>>(fn, wt, sumexp, labeling, lp_lab);
    ctc_kernel<<<NN, 64, 0, stream>>>(lp_lab, labeling, logit_lgts, labeling_lgts, nllb);
    reduce_kernel<<<1, 64, 0, stream>>>(nllb, out);

    (void)in_sizes; (void)n_in; (void)out_size; (void)ws_size;
}

// Round 11
// 164.280 us; speedup vs baseline: 1.1024x; 1.1024x over previous
//
#include <hip/hip_runtime.h>
#include <stdint.h>
#include <stddef.h>

// RadialCTC: cosine logits (norm_scale=32) -> log_softmax -> CTC(sum).
// Strategy: never materialize the (16384 x 1296) logits. GEMM (f16 MFMA)
// computes per-row sum(exp(logit)) fused in the epilogue; label log-probs via
// small f16 MFMA gather-GEMM; CTC alpha recursion one wave per sample.
// R4: gather on MFMA. R5: shfl=ds_bpermute ~120cyc; fp8 non-scaled = f16 rate.
// R6: DPP wave_shr neighbor access. R7: log-pair-fusion regressed; gather
//     single-barrier kept. R8: linear f32 FAILED (spread > f32 window).
// R9: linear f64 + exact pow2 renorm every 4 steps: ~30us (f64 chain).
// R10: BOTH changes regressed, reverted. But profile exposed the real gemm
//     bottleneck: SQ_LDS_BANK_CONFLICT=2.9M, MfmaUtil 18% - fragment reads
//     As[row*32+hi*8] have 64B row stride -> 16 lanes hit 2 banks (8-way,
//     2.94x per m136). LDS-read time ~282cyc/iter vs 77cyc MFMA.
// R11: XOR-swizzle LDS channel slot: staging fetches ch_dat = ch_mem ^
//     ((row>>1)&3) (lane->global map is free; LDS dest stays contiguous as
//     global_load_lds requires); readers use (hi^sw) with sw=(lm>>1)&3
//     (same for every fragment). 8-way -> 2-way (free). Applied to gemm
//     and gather.

typedef _Float16 f16;
typedef _Float16 f16x8 __attribute__((ext_vector_type(8)));
typedef float f32x4 __attribute__((ext_vector_type(4)));
typedef __attribute__((address_space(1))) void* as1_void_ptr;
typedef __attribute__((address_space(3))) void* as3_void_ptr;

#define TT 512
#define NN 32
#define CC 1296
#define DD 512
#define SS 30
#define CP 1408   // C padded to 11*128 for GEMM tiling (pad rows are zero)
#define LL 61     // 2*S+1 CTC states
#define NEGINF (-1e9f)
#define NORM_SCALE 32.0f
#define LOG2E 1.4426950408889634f
#define LN2   0.6931471805599453f

__device__ __forceinline__ float fexp2(float x) { return __builtin_amdgcn_exp2f(x); }
__device__ __forceinline__ float flog2(float x) { return __builtin_amdgcn_logf(x); }

// whole-wave shift-right-by-1 of a double (two 32-bit DPPs, ctrl 0x138 =
// WAVE_SHR1). Lane 0 receives +0.0.
__device__ __forceinline__ double dpp_sr1_zero64(double x) {
    long long b = __double_as_longlong(x);
    int lo = (int)(b & 0xFFFFFFFFLL);
    int hi = (int)(b >> 32);
    int lo2 = __builtin_amdgcn_update_dpp(0, lo, 0x138, 0xF, 0xF, false);
    int hi2 = __builtin_amdgcn_update_dpp(0, hi, 0x138, 0xF, 0xF, false);
    return __longlong_as_double(((long long)hi2 << 32) |
                                (unsigned long long)(unsigned int)lo2);
}
// one level of DPP row-shr int max (identity 0; operands are >=0 hi-words)
template <int CTRL>
__device__ __forceinline__ int dpp_imax_level(int m) {
    int t = __builtin_amdgcn_update_dpp(0, m, CTRL, 0xF, 0xF, false);
    return m > t ? m : t;
}

// ---- col sum-of-squares of W (D x C), partial over d-chunks, atomic ----
__global__ void colnorm_kernel(const float* __restrict__ W, float* __restrict__ ssq) {
    int c = blockIdx.x * 64 + threadIdx.x;
    if (c >= CC) return;
    int d0 = blockIdx.y * 64;
    float ss = 0.f;
    #pragma unroll 8
    for (int d = d0; d < d0 + 64; ++d) {
        float v = W[(size_t)d * CC + c];
        ss += v * v;
    }
    atomicAdd(&ssq[c], ss);
}

// ---- build padded transposed normalized weight w_t (CP x DD), f16 ----
__global__ void wt_kernel(const float* __restrict__ W, const float* __restrict__ ssq,
                          f16* __restrict__ wt) {
    int idx = blockIdx.x * 256 + threadIdx.x;   // idx < CP*DD
    int c = idx >> 9, d = idx & 511;
    float v = 0.f;
    if (c < CC) v = W[(size_t)d * CC + c] * rsqrtf(ssq[c]);
    wt[idx] = (f16)v;
}

// ---- feats row-normalize -> f16 (one wave per row) ----
__global__ __launch_bounds__(256) void fnorm_kernel(const float* __restrict__ feats,
                                                    f16* __restrict__ fn) {
    int wv = (blockIdx.x * 256 + threadIdx.x) >> 6;  // row id, 0..16383
    int lane = threadIdx.x & 63;
    const float4* src = (const float4*)(feats + (size_t)wv * DD) + lane * 2;
    float4 a = src[0], b = src[1];
    float ss = a.x*a.x + a.y*a.y + a.z*a.z + a.w*a.w
             + b.x*b.x + b.y*b.y + b.z*b.z + b.w*b.w;
    #pragma unroll
    for (int off = 32; off; off >>= 1) ss += __shfl_xor(ss, off);
    float r = rsqrtf(ss);
    f16x8 o;
    o[0]=(f16)(a.x*r); o[1]=(f16)(a.y*r); o[2]=(f16)(a.z*r); o[3]=(f16)(a.w*r);
    o[4]=(f16)(b.x*r); o[5]=(f16)(b.y*r); o[6]=(f16)(b.z*r); o[7]=(f16)(b.w*r);
    *(f16x8*)(fn + (size_t)wv * DD + lane * 8) = o;
}

// ---- MFMA GEMM (A: 16384x512 f16, B^T: 1408x512 f16) with fused
//      row-wise sum(exp(32*dot)) epilogue -> atomicAdd into sumexp[16384].
//      LDS channel-slot XOR swizzle: (row,ch) stored at slot ch^((row>>1)&3). ----
__global__ __launch_bounds__(256) void gemm_sumexp_kernel(const f16* __restrict__ A,
                                                          const f16* __restrict__ B,
                                                          float* __restrict__ sumexp) {
    __shared__ __align__(16) f16 As[128 * 32];
    __shared__ __align__(16) f16 Bs[128 * 32];
    int bm = blockIdx.x, bn = blockIdx.y;
    int tid = threadIdx.x;
    int w = tid >> 6, lane = tid & 63;
    int wm = w >> 1, wn = w & 1;           // 2x2 wave grid -> 64x64 per wave
    int lm = lane & 15, hi = lane >> 4;
    int sw = (lm >> 1) & 3;                // fragment-read channel swizzle
    f32x4 acc[4][4];
    f32x4 zero = {0.f, 0.f, 0.f, 0.f};
    #pragma unroll
    for (int i = 0; i < 4; ++i)
        #pragma unroll
        for (int j = 0; j < 4; ++j) acc[i][j] = zero;

    for (int kb = 0; kb < 16; ++kb) {      // K=512, BK=32 (one MFMA K-step)
        #pragma unroll
        for (int p = 0; p < 2; ++p) {
            int s = p * 256 + tid;         // segment id, 16B each; 512 segs/tile
            int row = s >> 2;
            int ch = (s & 3) ^ ((row >> 1) & 3);   // swizzled source channel
            const f16* ga = A + (size_t)(bm * 128 + row) * DD + kb * 32 + ch * 8;
            const f16* gb = B + (size_t)(bn * 128 + row) * DD + kb * 32 + ch * 8;
            // LDS dest = wave-uniform base + lane*16 (contiguous, required)
            __builtin_amdgcn_global_load_lds((as1_void_ptr)ga,
                (as3_void_ptr)&As[(p * 256 + w * 64) * 8], 16, 0, 0);
            __builtin_amdgcn_global_load_lds((as1_void_ptr)gb,
                (as3_void_ptr)&Bs[(p * 256 + w * 64) * 8], 16, 0, 0);
        }
        __syncthreads();
        f16x8 af[4], bf[4];
        #pragma unroll
        for (int i = 0; i < 4; ++i)
            af[i] = *(const f16x8*)&As[(wm * 64 + i * 16 + lm) * 32 + (hi ^ sw) * 8];
        #pragma unroll
        for (int j = 0; j < 4; ++j)
            bf[j] = *(const f16x8*)&Bs[(wn * 64 + j * 16 + lm) * 32 + (hi ^ sw) * 8];
        #pragma unroll
        for (int i = 0; i < 4; ++i)
            #pragma unroll
            for (int j = 0; j < 4; ++j)
                acc[i][j] = __builtin_amdgcn_mfma_f32_16x16x32_f16(af[i], bf[j], acc[i][j], 0, 0, 0);
        __syncthreads();
    }
    // epilogue: per-row sum of exp(32*logit) over this block's 128 columns
    #pragma unroll
    for (int i = 0; i < 4; ++i) {
        float rs[4] = {0.f, 0.f, 0.f, 0.f};
        #pragma unroll
        for (int j = 0; j < 4; ++j) {
            int c = bn * 128 + wn * 64 + j * 16 + lm;   // C/D: col = lane&15
            bool ok = (c < CC);
            #pragma unroll
            for (int r = 0; r < 4; ++r)
                rs[r] += ok ? fexp2(acc[i][j][r] * (NORM_SCALE * LOG2E)) : 0.f;
        }
        #pragma unroll
        for (int off = 1; off < 16; off <<= 1) {        // sum over 16 cols
            #pragma unroll
            for (int r = 0; r < 4; ++r) rs[r] += __shfl_xor(rs[r], off);
        }
        if (lm == 0) {
            int rowb = bm * 128 + wm * 64 + i * 16 + hi * 4;  // row = quad*4+reg
            #pragma unroll
            for (int r = 0; r < 4; ++r) atomicAdd(&sumexp[rowb + r], rs[r]);
        }
    }
}

// ---- gather-GEMM (f16): per (n, 64-t chunk), P = Fn(64x512) x Wlab^T(32x512).
//      All 16 K-tiles staged up-front (A 64KB + B 32KB LDS), ONE barrier.
//      Same LDS channel-slot XOR swizzle as gemm. ----
__global__ __launch_bounds__(256) void gather_kernel(const f16* __restrict__ fn,
                                                     const f16* __restrict__ wt,
                                                     const float* __restrict__ sumexp,
                                                     const int* __restrict__ labels,
                                                     float* __restrict__ lp_lab) {
    __shared__ __align__(16) f16 Bs[16 * 32 * 32];   // 32 KB: [kb][row][slot]
    __shared__ __align__(16) f16 As[16 * 64 * 32];   // 64 KB: [kb][row][slot]
    __shared__ float ls2[64];
    int n = blockIdx.x, t0 = blockIdx.y * 64;
    int tid = threadIdx.x;
    int w = tid >> 6, lane = tid & 63;
    int lm = lane & 15, hi = lane >> 4;
    int sw = (lm >> 1) & 3;

    #pragma unroll
    for (int it = 0; it < 8; ++it) {       // B: 2048 segs of 16B
        int s = it * 256 + tid;            // kb = s>>7, row = (s>>2)&31
        int row = (s >> 2) & 31;
        int ch = (s & 3) ^ ((row >> 1) & 3);
        int cls = (row == 0 || row > SS) ? 0 : labels[n * SS + row - 1];
        const f16* gb = wt + (size_t)cls * DD + (s >> 7) * 32 + ch * 8;
        __builtin_amdgcn_global_load_lds((as1_void_ptr)gb,
            (as3_void_ptr)&Bs[(it * 256 + w * 64) * 8], 16, 0, 0);
    }
    #pragma unroll
    for (int it = 0; it < 16; ++it) {      // A: 4096 segs of 16B
        int s = it * 256 + tid;            // kb = s>>8, row = (s>>2)&63
        int kb = s >> 8, row = (s >> 2) & 63;
        int ch = (s & 3) ^ ((row >> 1) & 3);
        const f16* ga = fn + (size_t)((t0 + row) * NN + n) * DD + kb * 32 + ch * 8;
        __builtin_amdgcn_global_load_lds((as1_void_ptr)ga,
            (as3_void_ptr)&As[(it * 256 + w * 64) * 8], 16, 0, 0);
    }
    if (tid < 64) ls2[tid] = flog2(sumexp[(size_t)(t0 + tid) * NN + n]);
    __syncthreads();

    f32x4 acc[2];
    acc[0] = (f32x4){0.f, 0.f, 0.f, 0.f};
    acc[1] = (f32x4){0.f, 0.f, 0.f, 0.f};
    #pragma unroll
    for (int kb = 0; kb < 16; ++kb) {
        f16x8 af  = *(const f16x8*)&As[kb * 2048 + (w * 16 + lm) * 32 + (hi ^ sw) * 8];
        f16x8 bf0 = *(const f16x8*)&Bs[kb * 1024 + lm * 32 + (hi ^ sw) * 8];
        f16x8 bf1 = *(const f16x8*)&Bs[kb * 1024 + (16 + lm) * 32 + (hi ^ sw) * 8];
        acc[0] = __builtin_amdgcn_mfma_f32_16x16x32_f16(af, bf0, acc[0], 0, 0, 0);
        acc[1] = __builtin_amdgcn_mfma_f32_16x16x32_f16(af, bf1, acc[1], 0, 0, 0);
    }
    #pragma unroll
    for (int jn = 0; jn < 2; ++jn) {
        int j = jn * 16 + lm;
        if (j >= 31) continue;
        float* dst = lp_lab + ((size_t)n * 31 + j) * TT + t0;
        #pragma unroll
        for (int r = 0; r < 4; ++r) {
            int tl = w * 16 + hi * 4 + r;
            dst[tl] = acc[jn][r] * (NORM_SCALE * LOG2E) - ls2[tl];
        }
    }
}

// ---- CTC alpha recursion, LINEAR domain in f64: one wave/sample, lane=state.
//      beta = (b + b<<1 + skip*(b<<2)) * 2^lp; chain has no transcendentals.
//      Wave-uniform exact power-of-2 renorm every 4 steps (hi-word int max);
//      freeze handled by wave-uniform loop bound (Tin per-sample). ----
__global__ void ctc_kernel(const float* __restrict__ lp_lab, const int* __restrict__ labels,
                           const int* __restrict__ in_lens, const int* __restrict__ lab_lens,
                           float* __restrict__ nll) {
    int n = blockIdx.x;
    int s = threadIdx.x;     // 64 lanes; states 0..60 valid
    bool valid = s < LL;
    int ext = (valid && (s & 1)) ? labels[n * SS + (s >> 1)] : 0;
    int jmap = (valid && (s & 1)) ? ((s >> 1) + 1) : 0;   // state -> class slot
    int ext2 = __shfl_up(ext, 2);
    double skipd = ((s >= 2) && valid && (ext != ext2)) ? 1.0 : 0.0;
    int Tin = in_lens[n];    // wave-uniform; freeze == stop at t = Tin-1
    const float4* g0 = (const float4*)(lp_lab + ((size_t)n * 31 + jmap) * TT);

    float4 cur = g0[0];
    float4 nxt = g0[1];
    float4 nx2 = g0[2];
    double beta = (s <= 1) ? (double)fexp2(cur.x) : 0.0;
    int Mi = 0;              // running log2 scale: alpha = log2(beta) + Mi

    auto stepL = [&](float lp) {
        double P = (double)fexp2(lp);      // lp >= ~-60 bits here: f32-safe
        double b1 = dpp_sr1_zero64(beta);
        double b2 = dpp_sr1_zero64(b1);
        beta = (beta + b1 + b2 * skipd) * P;
    };
    auto renorm = [&]() {
        int h = (int)(__double_as_longlong(beta) >> 32);  // beta>=0: monotone
        h = dpp_imax_level<0x111>(h);        // row_shr:1
        h = dpp_imax_level<0x112>(h);        // row_shr:2
        h = dpp_imax_level<0x114>(h);        // row_shr:4
        h = dpp_imax_level<0x118>(h);        // row_shr:8 -> row max in 15/31/47/63
        int r0 = __builtin_amdgcn_readlane(h, 15);
        int r1 = __builtin_amdgcn_readlane(h, 31);
        int r2 = __builtin_amdgcn_readlane(h, 47);
        int r3 = __builtin_amdgcn_readlane(h, 63);
        int mx = max(max(r0, r1), max(r2, r3));
        int e11 = mx >> 20;                  // biased 11-bit exponent
        // exact scale 2^(1023-(e11-1023)): biased exponent 2046-e11
        double scale = __longlong_as_double((long long)(2046 - e11) << 52);
        beta *= scale;
        Mi += e11 - 1023;
    };

    // group 0: t = 1..3 (Tin >= 481, always full)
    stepL(cur.y); stepL(cur.z); stepL(cur.w);
    renorm();
    int remaining = Tin - 4;   // steps left (total steps = Tin-1)
    int g = 1;
    while (remaining >= 4) {
        cur = nxt; nxt = nx2;
        int gi = g + 2; if (gi > 127) gi = 127;
        nx2 = g0[gi];
        stepL(cur.x); stepL(cur.y); stepL(cur.z); stepL(cur.w);
        renorm();
        remaining -= 4; ++g;
    }
    cur = nxt;                 // tail 0..3 steps
    if (remaining > 0) stepL(cur.x);
    if (remaining > 1) stepL(cur.y);
    if (remaining > 2) stepL(cur.z);

    int Ln = 2 * lab_lens[n] + 1;
    double last  = __shfl(beta, Ln - 1);
    double last2 = __shfl(beta, Ln - 2);
    double sm = last + last2;
    // log2 from the double's own exponent+mantissa (no tiny-f64 -> f32 cast)
    long long bb = __double_as_longlong(sm);
    int e = (int)(bb >> 52) - 1023;
    double mant = __longlong_as_double((bb & 0xFFFFFFFFFFFFFLL) | (1023LL << 52));
    float v = -(flog2((float)mant) + (float)(e + Mi)) * LN2;
    if (s == 0) nll[n] = v;
}

__global__ void reduce_kernel(const float* __restrict__ nll, float* __restrict__ out) {
    int s = threadIdx.x;
    float v = (s < NN) ? nll[s] : 0.f;
    #pragma unroll
    for (int off = 32; off; off >>= 1) v += __shfl_xor(v, off);
    if (s == 0) out[0] = v;
}

extern "C" void kernel_launch(void* const* d_in, const int* in_sizes, int n_in,
                              void* d_out, int out_size, void* d_ws, size_t ws_size,
                              hipStream_t stream) {
    const float* feats        = (const float*)d_in[0];
    const float* W            = (const float*)d_in[1];
    const int*   labeling     = (const int*)d_in[2];
    const int*   logit_lgts   = (const int*)d_in[3];
    const int*   labeling_lgts= (const int*)d_in[4];
    float* out = (float*)d_out;
    char* ws = (char*)d_ws;

    size_t off = 0;
    f16*   wt     = (f16*)(ws + off);   off += (size_t)CP * DD * 2;        // 1.44 MB
    f16*   fn     = (f16*)(ws + off);   off += (size_t)TT * NN * DD * 2;   // 16.8 MB
    float* ssq    = (float*)(ws + off); off += 1312 * 4;
    float* sumexp = (float*)(ws + off); off += (size_t)TT * NN * 4;        // 64 KB
    float* lp_lab = (float*)(ws + off); off += (size_t)NN * 31 * TT * 4;   // 2.0 MB
    float* nllb   = (float*)(ws + off); off += 64 * 4;

    hipMemsetAsync(ssq, 0, 1312 * 4, stream);
    hipMemsetAsync(sumexp, 0, (size_t)TT * NN * 4, stream);

    colnorm_kernel<<<dim3((CC + 63) / 64, 8), 64, 0, stream>>>(W, ssq);
    wt_kernel<<<(CP * DD) / 256, 256, 0, stream>>>(W, ssq, wt);
    fnorm_kernel<<<(TT * NN) / 4, 256, 0, stream>>>(feats, fn);
    gemm_sumexp_kernel<<<dim3(TT * NN / 128, CP / 128), 256, 0, stream>>>(fn, wt, sumexp);
    gather_kernel<<<dim3(NN, TT / 64), 256, 0, stream>>>(fn, wt, sumexp, labeling, lp_lab);
    ctc_kernel<<<NN, 64, 0, stream>>>(lp_lab, labeling, logit_lgts, labeling_lgts, nllb);
    reduce_kernel<<<1, 64, 0, stream>>>(nllb, out);

    (void)in_sizes; (void)n_in; (void)out_size; (void)ws_size;
}